// Round 10
// baseline (314.683 us; speedup 1.0000x reference)
//
#include <hip/hip_runtime.h>
#include <math.h>

#define NN 8000
#define NE 128000
#define NZ 10
#define KC 128
#define HID 64
#define NBIN 2048
#define FSTRIDE (NBIN + 4)

__global__ __launch_bounds__(256)
void kA(const float* __restrict__ w_embed, const float* __restrict__ w_up,
        const float* __restrict__ W1, const float* __restrict__ W2,
        const float* __restrict__ W3, const float* __restrict__ W4,
        const float* __restrict__ w_lin, const float* __restrict__ w_skip,
        const float* __restrict__ w_sym, const float* __restrict__ w_lin2,
        const float* __restrict__ w_readout, const float* __restrict__ ae,
        const int* __restrict__ species,
        float* __restrict__ Ft, float* __restrict__ out)
{
    const int b = blockIdx.x, tid = threadIdx.x;
    const int lane = tid & 63, wid = tid >> 6;

    if (b < 513) {
        // ---- self-contained table block: 4 bins (wave-per-bin) ----
        __shared__ float s_wr[KC], s_wl2r[KC];
        __shared__ float s_ws[NZ*KC];                 // wl2r[k]*w_sym[0][zr][k]
        __shared__ float s_hup[NZ*132], s_wfin[NZ*132];
        __shared__ __align__(16) float sT[4][HID];
        __shared__ float sQ[4][KC];

        // per-lane MLP weight columns (register-resident)
        float w1r[8], w2r[HID], w3r[HID];
        #pragma unroll
        for (int i = 0; i < 8; ++i) w1r[i] = W1[i*HID + lane];
        #pragma unroll
        for (int k = 0; k < HID; ++k) w2r[k] = W2[k*HID + lane];
        #pragma unroll
        for (int k = 0; k < HID; ++k) w3r[k] = W3[k*HID + lane];

        if (tid < KC) s_wr[tid] = w_readout[tid];
        __syncthreads();
        // wl2r[t] = dot(w_lin2[0][t], wr)
        if (tid < KC) {
            const float* row = w_lin2 + tid*KC;
            float a0=0.f,a1=0.f,a2=0.f,a3=0.f;
            for (int j = 0; j < KC; j += 4) {
                const float4 wv = *reinterpret_cast<const float4*>(row + j);
                const float4 wr = *reinterpret_cast<const float4*>(&s_wr[j]);
                a0 = fmaf(wv.x, wr.x, a0); a1 = fmaf(wv.y, wr.y, a1);
                a2 = fmaf(wv.z, wr.z, a2); a3 = fmaf(wv.w, wr.w, a3);
            }
            s_wl2r[tid] = (a0+a1)+(a2+a3);
        }
        __syncthreads();
        // wl2sym + hup
        for (int i = tid; i < NZ*KC; i += 256)
            s_ws[i] = s_wl2r[i & 127] * w_sym[i];     // w_sym[0] = [zr][k]
        for (int i = tid; i < NZ*KC; i += 256) {
            const int z = i >> 7, t = i & 127;
            float e0 = 0.f, e1 = 0.f;
            for (int kp = 0; kp < KC; kp += 2) {
                e0 = fmaf(w_embed[z*KC + kp],     w_up[kp*KC + t],     e0);
                e1 = fmaf(w_embed[z*KC + kp + 1], w_up[(kp+1)*KC + t], e1);
            }
            s_hup[z*132 + t] = e0 + e1;
        }
        __syncthreads();
        // wfin[zr][t] = dot(w_lin[t], wl2sym[zr])
        for (int i = tid; i < NZ*KC; i += 256) {
            const int zr = i >> 7, t = i & 127;
            const float* row = w_lin + t*KC;
            const float* wsz = s_ws + zr*KC;
            float a0=0.f,a1=0.f,a2=0.f,a3=0.f;
            for (int k = 0; k < KC; k += 4) {
                const float4 wv = *reinterpret_cast<const float4*>(row + k);
                a0 = fmaf(wv.x, wsz[k+0], a0); a1 = fmaf(wv.y, wsz[k+1], a1);
                a2 = fmaf(wv.z, wsz[k+2], a2); a3 = fmaf(wv.w, wsz[k+3], a3);
            }
            s_wfin[zr*132 + t] = (a0+a1)+(a2+a3);
        }
        __syncthreads();   // last block-wide sync; bin phase is wave-local

        const int bin = b*4 + wid;
        if (bin <= NBIN) {
            const float x = fmaxf((float)bin / (float)NBIN, 1e-6f);
            float env = 0.f;
            if (x < 1.f) {
                const float x2 = x*x, x5 = x2*x2*x;
                env = 1.0f + x5*(-21.0f + x*(35.0f - 15.0f*x));
            }
            float s1, c1;
            __sincosf(3.14159265358979323846f * x, &s1, &c1);
            const float tc   = 2.0f*c1;
            const float pref = 0.632455532033675866f * env / (5.0f*x);

            float z1 = 0.f;
            {
                float sp = 0.f, sc = s1;
                #pragma unroll
                for (int q = 0; q < 8; ++q) {
                    z1 = fmaf(sc * pref, w1r[q], z1);
                    const float nx = tc*sc - sp; sp = sc; sc = nx;
                }
            }
            const float t1 = z1 / (1.f + __expf(-z1));
            __builtin_amdgcn_wave_barrier();
            sT[wid][lane] = t1;
            __builtin_amdgcn_wave_barrier();

            float a0=0.f,a1=0.f,a2=0.f,a3=0.f;
            #pragma unroll
            for (int q = 0; q < 16; ++q) {
                const float4 tv = *reinterpret_cast<const float4*>(&sT[wid][q*4]);
                a0 = fmaf(tv.x, w2r[4*q+0], a0);
                a1 = fmaf(tv.y, w2r[4*q+1], a1);
                a2 = fmaf(tv.z, w2r[4*q+2], a2);
                a3 = fmaf(tv.w, w2r[4*q+3], a3);
            }
            const float z2 = (a0+a1)+(a2+a3);
            const float t2 = z2 / (1.f + __expf(-z2));
            __builtin_amdgcn_wave_barrier();
            sT[wid][lane] = t2;
            __builtin_amdgcn_wave_barrier();

            a0=0.f; a1=0.f; a2=0.f; a3=0.f;
            #pragma unroll
            for (int q = 0; q < 16; ++q) {
                const float4 tv = *reinterpret_cast<const float4*>(&sT[wid][q*4]);
                a0 = fmaf(tv.x, w3r[4*q+0], a0);
                a1 = fmaf(tv.y, w3r[4*q+1], a1);
                a2 = fmaf(tv.z, w3r[4*q+2], a2);
                a3 = fmaf(tv.w, w3r[4*q+3], a3);
            }
            const float z3 = (a0+a1)+(a2+a3);
            const float t3 = z3 / (1.f + __expf(-z3));
            __builtin_amdgcn_wave_barrier();
            sT[wid][lane] = t3;
            __builtin_amdgcn_wave_barrier();

            // Q[kp] = sum_c t3[c] * W4[c][4kp]  (l=0 slice, stride-4 gather, L2)
            float q0 = 0.f, q1 = 0.f;
            #pragma unroll 8
            for (int c = 0; c < HID; ++c) {
                const float t3c = sT[wid][c];
                const float* w4c = W4 + c*(KC*4);
                q0 = fmaf(t3c, w4c[4*lane],       q0);
                q1 = fmaf(t3c, w4c[256 + 4*lane], q1);
            }
            sQ[wid][lane]      = q0;
            sQ[wid][64 + lane] = q1;
            __builtin_amdgcn_wave_barrier();

            // F[p][bin], p per lane (2 rounds)
            #pragma unroll
            for (int rr = 0; rr < 2; ++rr) {
                const int p = lane + rr*64;
                if (p < NZ*NZ) {
                    const int zs = (p/NZ)*132, zr = (p%NZ)*132;
                    float acc = 0.f;
                    #pragma unroll 8
                    for (int kp = 0; kp < KC; ++kp)
                        acc = fmaf(s_hup[zs+kp]*s_wfin[zr+kp], sQ[wid][kp], acc);
                    Ft[p*FSTRIDE + bin] = acc * (1.0f/16.0f);
                }
            }
        }
    } else {
        // ---- init blocks: base[z] (redundant) + out init ----
        __shared__ float s_base[NZ];
        __shared__ float s_wr[KC], s_we[KC];
        __shared__ float s_red[256];
        if (tid < KC) s_wr[tid] = w_readout[tid];
        for (int z = 0; z < NZ; ++z) {
            if (tid < KC) s_we[tid] = w_embed[z*KC + tid];
            __syncthreads();
            float part = 0.f;
            for (int i = tid; i < KC*KC; i += 256)
                part = fmaf(w_skip[z*KC*KC + i], s_wr[i & 127] * s_we[i >> 7], part);
            s_red[tid] = part; __syncthreads();
            for (int s = 128; s > 0; s >>= 1) {
                if (tid < s) s_red[tid] += s_red[tid + s];
                __syncthreads();
            }
            if (tid == 0) s_base[z] = ae[z] + rsqrtf(10.f) * s_red[0];
            __syncthreads();
        }
        const int n = (b - 513)*256 + tid;
        if (n < NN) out[n] = s_base[species[n]];
    }
}

// ---- kE: one edge per thread -> r -> table lerp -> atomicAdd ----
__global__ __launch_bounds__(256)
void kE(const float* __restrict__ pos, const float* __restrict__ shifts,
        const int* __restrict__ eidx, const int* __restrict__ species,
        const float* __restrict__ Ft, float* __restrict__ out)
{
    const int e = blockIdx.x*256 + threadIdx.x;   // 500*256 = 128000 exactly
    const int sI = eidx[e];
    const int rI = eidx[NE + e];
    const float* pS = pos + 3*sI;
    const float* pR = pos + 3*rI;
    const float* sh = shifts + 3*e;
    const float dx = pR[0] - pS[0] + sh[0];
    const float dy = pR[1] - pS[1] + sh[1];
    const float dz = pR[2] - pS[2] + sh[2];
    const float r2 = dx*dx + dy*dy + dz*dz + 1e-9f;
    const float x  = sqrtf(r2) * 0.2f;
    if (x < 1.f) {
        const float xb = x * (float)NBIN;
        const int   b0 = (int)xb;
        const float fr = xb - (float)b0;
        const int   p  = species[sI]*NZ + species[rI];
        const float* row = Ft + p*FSTRIDE + b0;
        const float F0 = row[0], F1 = row[1];
        atomicAdd(&out[rI], fmaf(fr, F1 - F0, F0));
    }
}

extern "C" void kernel_launch(void* const* d_in, const int* in_sizes, int n_in,
                              void* d_out, int out_size, void* d_ws, size_t ws_size,
                              hipStream_t stream)
{
    const float* positions  = (const float*)d_in[0];
    const float* shifts     = (const float*)d_in[1];
    const int*   edge_index = (const int*)  d_in[2];
    const int*   species    = (const int*)  d_in[3];
    const float* ae         = (const float*)d_in[4];
    const float* w_embed    = (const float*)d_in[5];
    const float* w_up       = (const float*)d_in[6];
    const float* W1         = (const float*)d_in[7];
    const float* W2         = (const float*)d_in[8];
    const float* W3         = (const float*)d_in[9];
    const float* W4         = (const float*)d_in[10];
    const float* w_lin      = (const float*)d_in[11];
    const float* w_skip     = (const float*)d_in[12];
    const float* w_sym      = (const float*)d_in[13];
    const float* w_lin2     = (const float*)d_in[14];
    const float* w_readout  = (const float*)d_in[15];
    float* out = (float*)d_out;
    float* Ft  = (float*)d_ws;

    kA<<<513 + 32, 256, 0, stream>>>(w_embed, w_up, W1, W2, W3, W4,
                                     w_lin, w_skip, w_sym, w_lin2,
                                     w_readout, ae, species, Ft, out);
    kE<<<NE/256, 256, 0, stream>>>(positions, shifts, edge_index, species,
                                   Ft, out);
}

// Round 16
// 122.338 us; speedup vs baseline: 2.5722x; 2.5722x over previous
//
#include <hip/hip_runtime.h>
#include <math.h>

#define NN 8000
#define NE 128000
#define NZ 10
#define KC 128
#define HID 64
#define NBIN 512
#define FSTRIDE (NBIN + 4)

// ws float offsets
#define WS_WL2R 0        // 128
#define WS_BASE 128      // 16
#define WS_HUP  144      // 1280
#define WS_WFIN 1424     // 1280
#define WS_W4L0 2704     // 64*128 = 8192
#define WS_F    10896    // 100*FSTRIDE

__device__ __forceinline__ float wave_sum(float p) {
    #pragma unroll
    for (int off = 32; off > 0; off >>= 1) p += __shfl_xor(p, off);
    return p;
}

// ---- K1 (68 blocks): wl2r rows | hup | base | W4 l=0 extract ----
__global__ __launch_bounds__(256)
void k1(const float* __restrict__ w_embed, const float* __restrict__ w_up,
        const float* __restrict__ w_lin2, const float* __restrict__ w_readout,
        const float* __restrict__ w_skip, const float* __restrict__ W4,
        const float* __restrict__ ae, float* __restrict__ ws)
{
    const int b = blockIdx.x, tid = threadIdx.x;
    const int lane = tid & 63, wid = tid >> 6;
    if (b < 32) {                    // wl2r[r] = dot(w_lin2[0][r], w_readout)
        const int r = b*4 + wid;
        const float2 wr = *reinterpret_cast<const float2*>(w_readout + 2*lane);
        const float2 wl = *reinterpret_cast<const float2*>(w_lin2 + r*KC + 2*lane);
        const float p = wave_sum(wl.x*wr.x + wl.y*wr.y);
        if (lane == 0) ws[WS_WL2R + r] = p;
    } else if (b < 42) {             // hup[z][t] = dot(w_embed[z], w_up[:,t])
        const int z = b - 32;
        if (tid < KC) {
            float acc = 0.f;
            #pragma unroll 8
            for (int kp = 0; kp < KC; ++kp)
                acc = fmaf(w_embed[z*KC + kp], w_up[kp*KC + tid], acc);
            ws[WS_HUP + z*KC + tid] = acc;
        }
    } else if (b < 52) {             // base[z]
        const int z = b - 42;
        __shared__ float s_wr[KC], s_we[KC];
        __shared__ float s_red[256];
        if (tid < KC) { s_wr[tid] = w_readout[tid]; s_we[tid] = w_embed[z*KC + tid]; }
        __syncthreads();
        float part = 0.f;
        for (int i = tid; i < KC*KC; i += 256)
            part = fmaf(w_skip[z*KC*KC + i], s_wr[i & 127] * s_we[i >> 7], part);
        s_red[tid] = part; __syncthreads();
        for (int s = 128; s > 0; s >>= 1) {
            if (tid < s) s_red[tid] += s_red[tid + s];
            __syncthreads();
        }
        if (tid == 0) ws[WS_BASE + z] = ae[z] + rsqrtf(10.f) * s_red[0];
    } else {                          // dense W4 l=0 slice: 16 blocks, wave-per-c
        const int c = (b - 52)*4 + wid;
        ws[WS_W4L0 + c*KC + lane]      = W4[c*(KC*4) + 4*lane];
        ws[WS_W4L0 + c*KC + 64 + lane] = W4[c*(KC*4) + 256 + 4*lane];
    }
}

// ---- K2 (352 blocks): wfin rows (1280 wave-tasks) | out init ----
__global__ __launch_bounds__(256)
void k2(const float* __restrict__ w_lin, const float* __restrict__ w_sym,
        const int* __restrict__ species, float* __restrict__ ws,
        float* __restrict__ out)
{
    const int b = blockIdx.x, tid = threadIdx.x;
    const int lane = tid & 63, wid = tid >> 6;
    if (b < 320) {                   // idx = zr*128 + t
        const int idx = b*4 + wid;
        const int zr = idx >> 7, t = idx & 127;
        const float2 wl2 = *reinterpret_cast<const float2*>(ws + WS_WL2R + 2*lane);
        const float2 sy  = *reinterpret_cast<const float2*>(w_sym + zr*KC + 2*lane);
        const float2 wl  = *reinterpret_cast<const float2*>(w_lin + t*KC + 2*lane);
        const float p = wave_sum(wl.x*(wl2.x*sy.x) + wl.y*(wl2.y*sy.y));
        if (lane == 0) ws[WS_WFIN + idx] = p;
    } else {
        const int n = (b - 320)*256 + tid;
        if (n < NN) out[n] = ws[WS_BASE + species[n]];
    }
}

// ---- kTab: wave-per-bin MLP -> Q[kp] -> F[p][bin] with p-per-lane ----
__global__ __launch_bounds__(256)
void kTab(const float* __restrict__ W1, const float* __restrict__ W2,
          const float* __restrict__ W3, const float* __restrict__ ws,
          float* __restrict__ Ft)
{
    __shared__ float sHup[NZ*132];    // stride 132: <=2-way bank alias (free)
    __shared__ float sWfin[NZ*132];
    __shared__ __align__(16) float sT[4][HID];
    __shared__ float sQ[4][KC];
    const int tid = threadIdx.x, lane = tid & 63, wid = tid >> 6;

    float w1r[8], w2r[HID], w3r[HID];
    #pragma unroll
    for (int i = 0; i < 8; ++i) w1r[i] = W1[i*HID + lane];
    #pragma unroll
    for (int k = 0; k < HID; ++k) w2r[k] = W2[k*HID + lane];
    #pragma unroll
    for (int k = 0; k < HID; ++k) w3r[k] = W3[k*HID + lane];

    for (int i = tid; i < NZ*KC; i += 256) {
        sHup [(i >> 7)*132 + (i & 127)] = ws[WS_HUP  + i];
        sWfin[(i >> 7)*132 + (i & 127)] = ws[WS_WFIN + i];
    }
    __syncthreads();                  // no block syncs after this point

    const int bin = blockIdx.x*4 + wid;
    if (bin > NBIN) return;
    const float x = fmaxf((float)bin / (float)NBIN, 1e-6f);

    float env = 0.f;
    if (x < 1.f) {
        const float x2 = x*x, x5 = x2*x2*x;
        env = 1.0f + x5*(-21.0f + x*(35.0f - 15.0f*x));
    }
    float s1, c1;
    __sincosf(3.14159265358979323846f * x, &s1, &c1);
    const float tc   = 2.0f*c1;
    const float pref = 0.632455532033675866f * env / (5.0f*x);

    float z1 = 0.f;
    {
        float sp = 0.f, sc = s1;
        #pragma unroll
        for (int b = 0; b < 8; ++b) {
            z1 = fmaf(sc * pref, w1r[b], z1);
            const float nx = tc*sc - sp; sp = sc; sc = nx;
        }
    }
    const float t1 = z1 / (1.f + __expf(-z1));
    __builtin_amdgcn_wave_barrier();
    sT[wid][lane] = t1;
    __builtin_amdgcn_wave_barrier();

    float a0=0.f, a1=0.f, a2=0.f, a3=0.f;
    #pragma unroll
    for (int q = 0; q < 16; ++q) {
        const float4 tv = *reinterpret_cast<const float4*>(&sT[wid][q*4]);
        a0 = fmaf(tv.x, w2r[4*q+0], a0);
        a1 = fmaf(tv.y, w2r[4*q+1], a1);
        a2 = fmaf(tv.z, w2r[4*q+2], a2);
        a3 = fmaf(tv.w, w2r[4*q+3], a3);
    }
    const float z2 = (a0+a1)+(a2+a3);
    const float t2 = z2 / (1.f + __expf(-z2));
    __builtin_amdgcn_wave_barrier();
    sT[wid][lane] = t2;
    __builtin_amdgcn_wave_barrier();

    a0=0.f; a1=0.f; a2=0.f; a3=0.f;
    #pragma unroll
    for (int q = 0; q < 16; ++q) {
        const float4 tv = *reinterpret_cast<const float4*>(&sT[wid][q*4]);
        a0 = fmaf(tv.x, w3r[4*q+0], a0);
        a1 = fmaf(tv.y, w3r[4*q+1], a1);
        a2 = fmaf(tv.z, w3r[4*q+2], a2);
        a3 = fmaf(tv.w, w3r[4*q+3], a3);
    }
    const float z3 = (a0+a1)+(a2+a3);
    const float t3 = z3 / (1.f + __expf(-z3));
    __builtin_amdgcn_wave_barrier();
    sT[wid][lane] = t3;
    __builtin_amdgcn_wave_barrier();

    // Q[kp] = sum_c t3[c] * W4l0[c][kp]   (coalesced 256B reads per c-step)
    float q0 = 0.f, q1 = 0.f;
    #pragma unroll 8
    for (int c = 0; c < HID; ++c) {
        const float t3c = sT[wid][c];
        q0 = fmaf(t3c, ws[WS_W4L0 + c*KC + lane],      q0);
        q1 = fmaf(t3c, ws[WS_W4L0 + c*KC + 64 + lane], q1);
    }
    sQ[wid][lane]      = q0;
    sQ[wid][64 + lane] = q1;
    __builtin_amdgcn_wave_barrier();

    // F[p][bin], p per lane (2 rounds), all operands LDS
    #pragma unroll
    for (int rr = 0; rr < 2; ++rr) {
        const int p = lane + rr*64;
        if (p < NZ*NZ) {
            const int zs = (p/NZ)*132, zr = (p%NZ)*132;
            float acc = 0.f;
            #pragma unroll 8
            for (int kp = 0; kp < KC; ++kp)
                acc = fmaf(sHup[zs+kp]*sWfin[zr+kp], sQ[wid][kp], acc);
            Ft[p*FSTRIDE + bin] = acc * (1.0f/16.0f);
        }
    }
}

// ---- kE: one edge per thread -> r -> table lerp -> atomicAdd ----
__global__ __launch_bounds__(256)
void kE(const float* __restrict__ pos, const float* __restrict__ shifts,
        const int* __restrict__ eidx, const int* __restrict__ species,
        const float* __restrict__ Ft, float* __restrict__ out)
{
    const int e = blockIdx.x*256 + threadIdx.x;   // 500*256 = 128000 exactly
    const int sI = eidx[e];
    const int rI = eidx[NE + e];
    const float* pS = pos + 3*sI;
    const float* pR = pos + 3*rI;
    const float* sh = shifts + 3*e;
    const float dx = pR[0] - pS[0] + sh[0];
    const float dy = pR[1] - pS[1] + sh[1];
    const float dz = pR[2] - pS[2] + sh[2];
    const float r2 = dx*dx + dy*dy + dz*dz + 1e-9f;
    const float x  = sqrtf(r2) * 0.2f;
    if (x < 1.f) {
        const float xb = x * (float)NBIN;
        const int   b0 = (int)xb;
        const float fr = xb - (float)b0;
        const int   p  = species[sI]*NZ + species[rI];
        const float* row = Ft + p*FSTRIDE + b0;
        const float F0 = row[0], F1 = row[1];
        atomicAdd(&out[rI], fmaf(fr, F1 - F0, F0));
    }
}

extern "C" void kernel_launch(void* const* d_in, const int* in_sizes, int n_in,
                              void* d_out, int out_size, void* d_ws, size_t ws_size,
                              hipStream_t stream)
{
    const float* positions  = (const float*)d_in[0];
    const float* shifts     = (const float*)d_in[1];
    const int*   edge_index = (const int*)  d_in[2];
    const int*   species    = (const int*)  d_in[3];
    const float* ae         = (const float*)d_in[4];
    const float* w_embed    = (const float*)d_in[5];
    const float* w_up       = (const float*)d_in[6];
    const float* W1         = (const float*)d_in[7];
    const float* W2         = (const float*)d_in[8];
    const float* W3         = (const float*)d_in[9];
    const float* W4         = (const float*)d_in[10];
    const float* w_lin      = (const float*)d_in[11];
    const float* w_skip     = (const float*)d_in[12];
    const float* w_sym      = (const float*)d_in[13];
    const float* w_lin2     = (const float*)d_in[14];
    const float* w_readout  = (const float*)d_in[15];
    float* out = (float*)d_out;
    float* ws  = (float*)d_ws;
    float* Ft  = ws + WS_F;

    k1<<<68, 256, 0, stream>>>(w_embed, w_up, w_lin2, w_readout, w_skip, W4, ae, ws);
    k2<<<352, 256, 0, stream>>>(w_lin, w_sym, species, ws, out);
    kTab<<<(NBIN + 4)/4, 256, 0, stream>>>(W1, W2, W3, ws, Ft);
    kE<<<NE/256, 256, 0, stream>>>(positions, shifts, edge_index, species,
                                   Ft, out);
}